// Round 2
// baseline (834.090 us; speedup 1.0000x reference)
//
#include <hip/hip_runtime.h>
#include <hip/hip_bf16.h>

// LightGCN encoder on MI355X.
// ref dtypes (device): user_emb/item_emb/adj_val = float32 (values bf16-rounded
// by the harness transfer), adj_row/adj_col = int32, drop_mask = bool/int32
// (runtime-detected), users/items = int64/int32 (runtime-detected),
// output = float32. Float width also runtime-detected as insurance.
//
// Pipeline (all per launch, deterministic):
//   detect fmt -> histogram kept edges -> scan -> scatter to CSR ->
//   concat/cast ego0 -> 3x (wave-per-row CSR SpMM, gather-add) -> scale.

#define NUSER 100000
#define NITEM 50000
#define NNODE 150000
#define DIM   64
#define NNZ   4000000
#define BATCH 16384
#define SCAN_BLOCKS 586   // ceil(NNODE/256)

typedef __hip_bfloat16 bf16;

__device__ __forceinline__ float loadF(const void* p, long i, int isbf16) {
    return isbf16 ? __bfloat162float(((const bf16*)p)[i]) : ((const float*)p)[i];
}

__device__ __forceinline__ bool keepE(const void* mask, int e, int isbyte) {
    return isbyte ? (((const unsigned char*)mask)[e] != 0)
                  : (((const int*)mask)[e] != 0);
}

// ---------------------------------------------------------------------------
// flags[0]: drop_mask is 1-byte. flags[1]: users/items are int64.
// flags[2]: float arrays are bf16 (insurance; expected 0 = f32).
// Pure function of d_in prefixes -> deterministic.
__global__ __launch_bounds__(256) void detect_fmt(const unsigned int* __restrict__ mask,
                                                  const unsigned int* __restrict__ users,
                                                  const unsigned int* __restrict__ adjv,
                                                  int* __restrict__ flags) {
    __shared__ int s[3];
    if (threadIdx.x < 3) s[threadIdx.x] = 0;
    __syncthreads();
    int c0 = 0, c1 = 0, c2 = 0;
    for (int i = threadIdx.x; i < 4096; i += 256) {
        // int32 0/1 mask -> word <= 1 always; packed bytes -> mostly > 1.
        c0 += (mask[i] > 1u) ? 1 : 0;
        // int64 indices (<2^31, LE) -> odd words all 0; int32 -> ~never 0.
        if (i & 1) c1 += (users[i] == 0u) ? 1 : 0;
        // even uint16 of adj_val: bf16 -> positive small exponent ~always;
        // f32 low mantissa bits -> random (~6% hit).
        unsigned lo = adjv[i] & 0xFFFFu;
        unsigned ex = (lo >> 7) & 0xFFu;
        c2 += ((lo >> 15) == 0u && ex >= 0x60u && ex <= 0x7Fu) ? 1 : 0;
    }
    atomicAdd(&s[0], c0); atomicAdd(&s[1], c1); atomicAdd(&s[2], c2);
    __syncthreads();
    if (threadIdx.x == 0) {
        flags[0] = (s[0] > 16) ? 1 : 0;
        flags[1] = (s[1] > 1024) ? 1 : 0;
        flags[2] = (s[2] > 3000) ? 1 : 0;
    }
}

// count[r] = number of kept edges with row == r
__global__ __launch_bounds__(256) void hist_kept(const void* __restrict__ mask,
                                                 const int* __restrict__ rows,
                                                 const int* __restrict__ flags,
                                                 int* __restrict__ count) {
    int e = blockIdx.x * 256 + threadIdx.x;
    if (e >= NNZ) return;
    if (keepE(mask, e, flags[0])) atomicAdd(&count[rows[e]], 1);
}

// per-block inclusive scan of count -> rowptr[i+1]; block totals -> partials
__global__ __launch_bounds__(256) void scan_blocks(const int* __restrict__ count,
                                                   int* __restrict__ rowptr,
                                                   int* __restrict__ partials) {
    __shared__ int s[256];
    int i = blockIdx.x * 256 + threadIdx.x;
    int v = (i < NNODE) ? count[i] : 0;
    s[threadIdx.x] = v;
    __syncthreads();
    for (int off = 1; off < 256; off <<= 1) {
        int t = (threadIdx.x >= off) ? s[threadIdx.x - off] : 0;
        __syncthreads();
        s[threadIdx.x] += t;
        __syncthreads();
    }
    if (i < NNODE) rowptr[i + 1] = s[threadIdx.x];
    if (threadIdx.x == 255) partials[blockIdx.x] = s[255];
}

// exclusive scan of block totals, in place (SCAN_BLOCKS <= 1024)
__global__ __launch_bounds__(1024) void scan_partials(int* __restrict__ partials) {
    __shared__ int s[1024];
    int v = (threadIdx.x < SCAN_BLOCKS) ? partials[threadIdx.x] : 0;
    s[threadIdx.x] = v;
    __syncthreads();
    for (int off = 1; off < 1024; off <<= 1) {
        int t = (threadIdx.x >= off) ? s[threadIdx.x - off] : 0;
        __syncthreads();
        s[threadIdx.x] += t;
        __syncthreads();
    }
    if (threadIdx.x < SCAN_BLOCKS) partials[threadIdx.x] = s[threadIdx.x] - v;
}

__global__ __launch_bounds__(256) void add_back(int* __restrict__ rowptr,
                                                const int* __restrict__ partials) {
    int i = blockIdx.x * 256 + threadIdx.x;
    if (i < NNODE) rowptr[i + 1] += partials[blockIdx.x];
    if (i == 0) rowptr[0] = 0;
}

// compact kept edges into CSR arrays (order within a row is arbitrary)
__global__ __launch_bounds__(256) void scatter_csr(const void* __restrict__ mask,
                                                   const int* __restrict__ rows,
                                                   const int* __restrict__ cols,
                                                   const void* __restrict__ adjv,
                                                   const int* __restrict__ flags,
                                                   const int* __restrict__ rowptr,
                                                   int* __restrict__ cursor,
                                                   int* __restrict__ cols_s,
                                                   float* __restrict__ vals_s) {
    int e = blockIdx.x * 256 + threadIdx.x;
    if (e >= NNZ) return;
    if (!keepE(mask, e, flags[0])) return;
    int r = rows[e];
    int pos = rowptr[r] + atomicAdd(&cursor[r], 1);
    cols_s[pos] = cols[e];
    vals_s[pos] = 2.0f * loadF(adjv, e, flags[2]);   // 1/(1-0.5) rescale
}

// A = f32(concat(user_emb, item_emb))
__global__ __launch_bounds__(256) void concat_cast(const void* __restrict__ ue,
                                                   const void* __restrict__ ie,
                                                   const int* __restrict__ flags,
                                                   float* __restrict__ A) {
    long i = (long)blockIdx.x * 256 + threadIdx.x;
    const long NU = (long)NUSER * DIM;
    if (i >= (long)NNODE * DIM) return;
    A[i] = (i < NU) ? loadF(ue, i, flags[2]) : loadF(ie, i - NU, flags[2]);
}

// dst[r,:] = sum_j vals[j] * src[cols[j],:]  -- one 64-lane wave per row
__global__ __launch_bounds__(256) void spmm_csr(const float* __restrict__ src,
                                                const int* __restrict__ rowptr,
                                                const int* __restrict__ cols_s,
                                                const float* __restrict__ vals_s,
                                                float* __restrict__ dst) {
    int r = blockIdx.x * 4 + (threadIdx.x >> 6);
    if (r >= NNODE) return;
    int d = threadIdx.x & 63;
    int j0 = rowptr[r], j1 = rowptr[r + 1];
    float acc = 0.0f;
    for (int j = j0; j < j1; ++j)
        acc += vals_s[j] * src[(size_t)cols_s[j] * DIM + d];
    dst[(size_t)r * DIM + d] = acc;
}

// acc[b,:] += table[node(b),:]
__global__ __launch_bounds__(256) void gather_add(const float* __restrict__ table,
                                                  const int* __restrict__ users,
                                                  const int* __restrict__ items,
                                                  const int* __restrict__ flags,
                                                  float* __restrict__ acc) {
    int t = blockIdx.x * 256 + threadIdx.x;
    if (t >= 2 * BATCH * DIM) return;
    int b = t >> 6;
    int d = t & 63;
    int sh = flags[1];  // int64: low word at stride 2 (values < 2^31, LE)
    long node;
    if (b < BATCH) node = (long)users[(size_t)b << sh];
    else           node = (long)NUSER + (long)items[(size_t)(b - BATCH) << sh];
    acc[t] += table[node * DIM + d];
}

__global__ __launch_bounds__(256) void finalize_f32(const float* __restrict__ acc,
                                                    float* __restrict__ out) {
    int t = blockIdx.x * 256 + threadIdx.x;
    if (t >= 2 * BATCH * DIM) return;
    out[t] = 0.25f * acc[t];
}

extern "C" void kernel_launch(void* const* d_in, const int* in_sizes, int n_in,
                              void* d_out, int out_size, void* d_ws, size_t ws_size,
                              hipStream_t stream) {
    const void* user_emb = d_in[0];
    const void* item_emb = d_in[1];
    const void* adj_val  = d_in[2];
    const int*  adj_row  = (const int*)d_in[3];
    const int*  adj_col  = (const int*)d_in[4];
    const void* drop_msk = d_in[5];
    const int*  users    = (const int*)d_in[6];
    const int*  items    = (const int*)d_in[7];
    float* out = (float*)d_out;

    // ws layout (256B-aligned regions), ~119 MB total
    char* ws = (char*)d_ws;
    size_t off = 0;
    int* flags = (int*)(ws + off);            off += 256;
    float* out_acc = (float*)(ws + off);      off += (size_t)2 * BATCH * DIM * 4;   // 8,388,608
    float* A = (float*)(ws + off);            off += (size_t)NNODE * DIM * 4;       // 38,400,000
    float* B = (float*)(ws + off);            off += (size_t)NNODE * DIM * 4;
    int* rowptr = (int*)(ws + off);           off += 600064;                        // NNODE+1 ints
    int* count = (int*)(ws + off);            off += 600064;
    int* cursor = (int*)(ws + off);           off += 600064;
    int* partials = (int*)(ws + off);         off += 4096;
    int* cols_s = (int*)(ws + off);           off += (size_t)NNZ * 4;               // worst case all kept
    float* vals_s = (float*)(ws + off);       off += (size_t)NNZ * 4;

    const int OUTN = 2 * BATCH * DIM;
    const int GOUT = (OUTN + 255) / 256;
    const int GEDGE = (NNZ + 255) / 256;

    hipMemsetAsync(count, 0, (size_t)NNODE * 4, stream);
    hipMemsetAsync(cursor, 0, (size_t)NNODE * 4, stream);
    hipMemsetAsync(out_acc, 0, (size_t)OUTN * 4, stream);

    detect_fmt<<<1, 256, 0, stream>>>((const unsigned int*)drop_msk,
                                      (const unsigned int*)users,
                                      (const unsigned int*)adj_val, flags);
    hist_kept<<<GEDGE, 256, 0, stream>>>(drop_msk, adj_row, flags, count);
    scan_blocks<<<SCAN_BLOCKS, 256, 0, stream>>>(count, rowptr, partials);
    scan_partials<<<1, 1024, 0, stream>>>(partials);
    add_back<<<SCAN_BLOCKS, 256, 0, stream>>>(rowptr, partials);
    scatter_csr<<<GEDGE, 256, 0, stream>>>(drop_msk, adj_row, adj_col, adj_val,
                                           flags, rowptr, cursor, cols_s, vals_s);
    concat_cast<<<((NNODE * DIM) + 255) / 256, 256, 0, stream>>>(user_emb, item_emb, flags, A);

    gather_add<<<GOUT, 256, 0, stream>>>(A, users, items, flags, out_acc);
    float* src = A;
    float* dst = B;
    for (int l = 0; l < 3; ++l) {
        spmm_csr<<<(NNODE + 3) / 4, 256, 0, stream>>>(src, rowptr, cols_s, vals_s, dst);
        gather_add<<<GOUT, 256, 0, stream>>>(dst, users, items, flags, out_acc);
        float* t = src; src = dst; dst = t;
    }
    finalize_f32<<<GOUT, 256, 0, stream>>>(out_acc, out);
}

// Round 4
// 553.848 us; speedup vs baseline: 1.5060x; 1.5060x over previous
//
#include <hip/hip_runtime.h>
#include <hip/hip_bf16.h>

// LightGCN encoder on MI355X.
// Device dtypes: user_emb/item_emb/adj_val = float32 (bf16-rounded values),
// adj_row/adj_col = int32, drop_mask = bool/int32 (runtime-detected),
// users/items = int64/int32 (runtime-detected), output = float32.
//
// Pipeline: detect fmt -> histogram kept edges -> scan -> scatter to CSR ->
// concat ego0 -> 3x (wave-per-row CSR SpMM w/ unroll-4 gathers, gather-add)
// -> scale. SpMM is latency-bound on table gathers; unroll-4 gives 4
// independent gathers in flight per wave (round-2 counters: VALUBusy 16%,
// HBM 17%, occupancy 73% => latency-bound, not BW-bound).

#define NUSER 100000
#define NITEM 50000
#define NNODE 150000
#define DIM   64
#define NNZ   4000000
#define BATCH 16384
#define SCAN_BLOCKS 586   // ceil(NNODE/256)

typedef __hip_bfloat16 bf16;
typedef float f4 __attribute__((ext_vector_type(4)));   // clang vector: ok for nontemporal

__device__ __forceinline__ float loadF(const void* p, long i, int isbf16) {
    return isbf16 ? __bfloat162float(((const bf16*)p)[i]) : ((const float*)p)[i];
}

__device__ __forceinline__ bool keepE(const void* mask, int e, int isbyte) {
    return isbyte ? (((const unsigned char*)mask)[e] != 0)
                  : (((const int*)mask)[e] != 0);
}

// ---------------------------------------------------------------------------
// flags[0]: drop_mask is 1-byte. flags[1]: users/items are int64.
// flags[2]: float arrays are bf16 (insurance; expected 0 = f32).
__global__ __launch_bounds__(256) void detect_fmt(const unsigned int* __restrict__ mask,
                                                  const unsigned int* __restrict__ users,
                                                  const unsigned int* __restrict__ adjv,
                                                  int* __restrict__ flags) {
    __shared__ int s[3];
    if (threadIdx.x < 3) s[threadIdx.x] = 0;
    __syncthreads();
    int c0 = 0, c1 = 0, c2 = 0;
    for (int i = threadIdx.x; i < 4096; i += 256) {
        c0 += (mask[i] > 1u) ? 1 : 0;
        if (i & 1) c1 += (users[i] == 0u) ? 1 : 0;
        unsigned lo = adjv[i] & 0xFFFFu;
        unsigned ex = (lo >> 7) & 0xFFu;
        c2 += ((lo >> 15) == 0u && ex >= 0x60u && ex <= 0x7Fu) ? 1 : 0;
    }
    atomicAdd(&s[0], c0); atomicAdd(&s[1], c1); atomicAdd(&s[2], c2);
    __syncthreads();
    if (threadIdx.x == 0) {
        flags[0] = (s[0] > 16) ? 1 : 0;
        flags[1] = (s[1] > 1024) ? 1 : 0;
        flags[2] = (s[2] > 3000) ? 1 : 0;
    }
}

__global__ __launch_bounds__(256) void hist_kept(const void* __restrict__ mask,
                                                 const int* __restrict__ rows,
                                                 const int* __restrict__ flags,
                                                 int* __restrict__ count) {
    int e = blockIdx.x * 256 + threadIdx.x;
    if (e >= NNZ) return;
    if (keepE(mask, e, flags[0])) atomicAdd(&count[rows[e]], 1);
}

__global__ __launch_bounds__(256) void scan_blocks(const int* __restrict__ count,
                                                   int* __restrict__ rowptr,
                                                   int* __restrict__ partials) {
    __shared__ int s[256];
    int i = blockIdx.x * 256 + threadIdx.x;
    int v = (i < NNODE) ? count[i] : 0;
    s[threadIdx.x] = v;
    __syncthreads();
    for (int off = 1; off < 256; off <<= 1) {
        int t = (threadIdx.x >= off) ? s[threadIdx.x - off] : 0;
        __syncthreads();
        s[threadIdx.x] += t;
        __syncthreads();
    }
    if (i < NNODE) rowptr[i + 1] = s[threadIdx.x];
    if (threadIdx.x == 255) partials[blockIdx.x] = s[255];
}

__global__ __launch_bounds__(1024) void scan_partials(int* __restrict__ partials) {
    __shared__ int s[1024];
    int v = (threadIdx.x < SCAN_BLOCKS) ? partials[threadIdx.x] : 0;
    s[threadIdx.x] = v;
    __syncthreads();
    for (int off = 1; off < 1024; off <<= 1) {
        int t = (threadIdx.x >= off) ? s[threadIdx.x - off] : 0;
        __syncthreads();
        s[threadIdx.x] += t;
        __syncthreads();
    }
    if (threadIdx.x < SCAN_BLOCKS) partials[threadIdx.x] = s[threadIdx.x] - v;
}

// rowptr[i+1] finalized; cursor[i] = rowptr[i] (scatter start positions)
__global__ __launch_bounds__(256) void add_back(int* __restrict__ rowptr,
                                                int* __restrict__ cursor,
                                                const int* __restrict__ partials) {
    int i = blockIdx.x * 256 + threadIdx.x;
    if (i >= NNODE) return;
    int v = rowptr[i + 1] + partials[blockIdx.x];
    rowptr[i + 1] = v;
    cursor[i + 1] = v;            // cursor sized NNODE+1
    if (i == 0) { rowptr[0] = 0; cursor[0] = 0; }
}

__global__ __launch_bounds__(256) void scatter_csr(const void* __restrict__ mask,
                                                   const int* __restrict__ rows,
                                                   const int* __restrict__ cols,
                                                   const void* __restrict__ adjv,
                                                   const int* __restrict__ flags,
                                                   int* __restrict__ cursor,
                                                   int* __restrict__ cols_s,
                                                   float* __restrict__ vals_s) {
    int e = blockIdx.x * 256 + threadIdx.x;
    if (e >= NNZ) return;
    if (!keepE(mask, e, flags[0])) return;
    int pos = atomicAdd(&cursor[rows[e]], 1);
    cols_s[pos] = cols[e];
    vals_s[pos] = 2.0f * loadF(adjv, e, flags[2]);   // 1/(1-0.5) rescale
}

// A = f32(concat(user_emb, item_emb)), float4 path for f32 input
__global__ __launch_bounds__(256) void concat_cast(const void* __restrict__ ue,
                                                   const void* __restrict__ ie,
                                                   const int* __restrict__ flags,
                                                   float* __restrict__ A) {
    long q = (long)blockIdx.x * 256 + threadIdx.x;   // float4 index
    const long NU4 = (long)NUSER * DIM / 4;
    const long NT4 = (long)NNODE * DIM / 4;
    if (q >= NT4) return;
    if (!flags[2]) {
        const f4* s = (q < NU4) ? (const f4*)ue : (const f4*)ie;
        long qi = (q < NU4) ? q : q - NU4;
        ((f4*)A)[q] = s[qi];
    } else {
        long i = q * 4;
        const long NU = NU4 * 4;
        for (int k = 0; k < 4; ++k)
            A[i + k] = (i + k < NU) ? loadF(ue, i + k, 1) : loadF(ie, i + k - NU, 1);
    }
}

// dst[r,:] = sum_j vals[j] * src[cols[j],:]
// One 64-lane wave per row (lane = dim). Unroll 4 => 4 gathers in flight.
__global__ __launch_bounds__(256) void spmm_csr(const float* __restrict__ src,
                                                const int* __restrict__ rowptr,
                                                const int* __restrict__ cols_s,
                                                const float* __restrict__ vals_s,
                                                float* __restrict__ dst) {
    int r = blockIdx.x * 4 + (threadIdx.x >> 6);
    if (r >= NNODE) return;
    int d = threadIdx.x & 63;
    int j0 = rowptr[r], j1 = rowptr[r + 1];
    float acc = 0.0f;
    int j = j0;
    for (; j + 4 <= j1; j += 4) {
        int   c0 = cols_s[j],     c1 = cols_s[j + 1];
        int   c2 = cols_s[j + 2], c3 = cols_s[j + 3];
        float v0 = vals_s[j],     v1 = vals_s[j + 1];
        float v2 = vals_s[j + 2], v3 = vals_s[j + 3];
        float s0 = src[(size_t)c0 * DIM + d];
        float s1 = src[(size_t)c1 * DIM + d];
        float s2 = src[(size_t)c2 * DIM + d];
        float s3 = src[(size_t)c3 * DIM + d];
        acc = fmaf(v0, s0, acc);
        acc = fmaf(v1, s1, acc);
        acc = fmaf(v2, s2, acc);
        acc = fmaf(v3, s3, acc);
    }
    for (; j < j1; ++j)
        acc = fmaf(vals_s[j], src[(size_t)cols_s[j] * DIM + d], acc);
    __builtin_nontemporal_store(acc, dst + (size_t)r * DIM + d);
}

// acc[b,:] += table[node(b),:]   (float4 per thread)
__global__ __launch_bounds__(256) void gather_add(const float* __restrict__ table,
                                                  const int* __restrict__ users,
                                                  const int* __restrict__ items,
                                                  const int* __restrict__ flags,
                                                  float* __restrict__ acc) {
    int t = blockIdx.x * 256 + threadIdx.x;          // float4 index
    if (t >= 2 * BATCH * DIM / 4) return;
    int b = t >> 4;              // 16 float4 per row
    int d4 = t & 15;
    int sh = flags[1];
    long node;
    if (b < BATCH) node = (long)users[(size_t)b << sh];
    else           node = (long)NUSER + (long)items[(size_t)(b - BATCH) << sh];
    const f4* row = (const f4*)(table + node * DIM);
    f4 a = ((f4*)acc)[t];
    a += row[d4];
    ((f4*)acc)[t] = a;
}

__global__ __launch_bounds__(256) void finalize_f32(const float* __restrict__ acc,
                                                    float* __restrict__ out) {
    int t = blockIdx.x * 256 + threadIdx.x;          // float4 index
    if (t >= 2 * BATCH * DIM / 4) return;
    f4 a = ((const f4*)acc)[t];
    a *= 0.25f;
    __builtin_nontemporal_store(a, (f4*)out + t);
}

extern "C" void kernel_launch(void* const* d_in, const int* in_sizes, int n_in,
                              void* d_out, int out_size, void* d_ws, size_t ws_size,
                              hipStream_t stream) {
    const void* user_emb = d_in[0];
    const void* item_emb = d_in[1];
    const void* adj_val  = d_in[2];
    const int*  adj_row  = (const int*)d_in[3];
    const int*  adj_col  = (const int*)d_in[4];
    const void* drop_msk = d_in[5];
    const int*  users    = (const int*)d_in[6];
    const int*  items    = (const int*)d_in[7];
    float* out = (float*)d_out;

    char* ws = (char*)d_ws;
    size_t off = 0;
    int* flags = (int*)(ws + off);            off += 256;
    float* out_acc = (float*)(ws + off);      off += (size_t)2 * BATCH * DIM * 4;   // 8 MB
    float* A = (float*)(ws + off);            off += (size_t)NNODE * DIM * 4;       // 38.4 MB
    float* B = (float*)(ws + off);            off += (size_t)NNODE * DIM * 4;       // 38.4 MB
    int* rowptr = (int*)(ws + off);           off += 600064;
    int* count = (int*)(ws + off);            off += 600064;
    int* cursor = (int*)(ws + off);           off += 600064;
    int* partials = (int*)(ws + off);         off += 4096;
    int* cols_s = (int*)(ws + off);           off += (size_t)NNZ * 4;
    float* vals_s = (float*)(ws + off);       off += (size_t)NNZ * 4;

    const int OUTN4 = 2 * BATCH * DIM / 4;            // 524288
    const int GOUT = (OUTN4 + 255) / 256;             // 2048
    const int GEDGE = (NNZ + 255) / 256;

    (void)hipMemsetAsync(count, 0, (size_t)NNODE * 4, stream);
    (void)hipMemsetAsync(out_acc, 0, (size_t)2 * BATCH * DIM * 4, stream);

    detect_fmt<<<1, 256, 0, stream>>>((const unsigned int*)drop_msk,
                                      (const unsigned int*)users,
                                      (const unsigned int*)adj_val, flags);
    hist_kept<<<GEDGE, 256, 0, stream>>>(drop_msk, adj_row, flags, count);
    scan_blocks<<<SCAN_BLOCKS, 256, 0, stream>>>(count, rowptr, partials);
    scan_partials<<<1, 1024, 0, stream>>>(partials);
    add_back<<<SCAN_BLOCKS, 256, 0, stream>>>(rowptr, cursor, partials);
    scatter_csr<<<GEDGE, 256, 0, stream>>>(drop_msk, adj_row, adj_col, adj_val,
                                           flags, cursor, cols_s, vals_s);
    concat_cast<<<((NNODE * DIM / 4) + 255) / 256, 256, 0, stream>>>(user_emb, item_emb,
                                                                     flags, A);

    gather_add<<<GOUT, 256, 0, stream>>>(A, users, items, flags, out_acc);
    float* src = A;
    float* dst = B;
    for (int l = 0; l < 3; ++l) {
        spmm_csr<<<(NNODE + 3) / 4, 256, 0, stream>>>(src, rowptr, cols_s, vals_s, dst);
        gather_add<<<GOUT, 256, 0, stream>>>(dst, users, items, flags, out_acc);
        float* t = src; src = dst; dst = t;
    }
    finalize_f32<<<GOUT, 256, 0, stream>>>(out_acc, out);
}

// Round 5
// 482.353 us; speedup vs baseline: 1.7292x; 1.1482x over previous
//
#include <hip/hip_runtime.h>
#include <hip/hip_bf16.h>

// LightGCN encoder on MI355X.
// Device dtypes: user_emb/item_emb/adj_val = float32 (bf16-rounded values),
// adj_row/adj_col = int32, drop_mask = bool/int32 (runtime-detected),
// users/items = int64/int32 (runtime-detected), output = float32.
//
// Pipeline: detect fmt -> histogram kept edges -> scan -> scatter packed
// (col,val) u64 CSR -> 3x (wave-per-row SpMM: float4 gathers, 4 edge-quarters
// per wave, unroll-2) -> gather-adds -> fused final gather+scale.
// Round-4 evidence: scatter was write-amplified 12x (two 4B scattered stores);
// packing to one 8B store halves dirtied lines. SpMM is LLC-latency-bound;
// quarter-wave f4 scheme puts 8 gathers in flight per wave.

#define NUSER 100000
#define NITEM 50000
#define NNODE 150000
#define DIM   64
#define NNZ   4000000
#define BATCH 16384
#define SCAN_BLOCKS 586   // ceil(NNODE/256)

typedef __hip_bfloat16 bf16;
typedef unsigned long long u64;
typedef float f4 __attribute__((ext_vector_type(4)));

__device__ __forceinline__ float loadF(const void* p, long i, int isbf16) {
    return isbf16 ? __bfloat162float(((const bf16*)p)[i]) : ((const float*)p)[i];
}

__device__ __forceinline__ bool keepE(const void* mask, int e, int isbyte) {
    return isbyte ? (((const unsigned char*)mask)[e] != 0)
                  : (((const int*)mask)[e] != 0);
}

// ---------------------------------------------------------------------------
// flags[0]: drop_mask is 1-byte. flags[1]: users/items are int64.
// flags[2]: float arrays are bf16 (insurance; expected 0 = f32).
__global__ __launch_bounds__(256) void detect_fmt(const unsigned int* __restrict__ mask,
                                                  const unsigned int* __restrict__ users,
                                                  const unsigned int* __restrict__ adjv,
                                                  int* __restrict__ flags) {
    __shared__ int s[3];
    if (threadIdx.x < 3) s[threadIdx.x] = 0;
    __syncthreads();
    int c0 = 0, c1 = 0, c2 = 0;
    for (int i = threadIdx.x; i < 4096; i += 256) {
        c0 += (mask[i] > 1u) ? 1 : 0;
        if (i & 1) c1 += (users[i] == 0u) ? 1 : 0;
        unsigned lo = adjv[i] & 0xFFFFu;
        unsigned ex = (lo >> 7) & 0xFFu;
        c2 += ((lo >> 15) == 0u && ex >= 0x60u && ex <= 0x7Fu) ? 1 : 0;
    }
    atomicAdd(&s[0], c0); atomicAdd(&s[1], c1); atomicAdd(&s[2], c2);
    __syncthreads();
    if (threadIdx.x == 0) {
        flags[0] = (s[0] > 16) ? 1 : 0;
        flags[1] = (s[1] > 1024) ? 1 : 0;
        flags[2] = (s[2] > 3000) ? 1 : 0;
    }
}

__global__ __launch_bounds__(256) void hist_kept(const void* __restrict__ mask,
                                                 const int* __restrict__ rows,
                                                 const int* __restrict__ flags,
                                                 int* __restrict__ count) {
    int e = blockIdx.x * 256 + threadIdx.x;
    if (e >= NNZ) return;
    if (keepE(mask, e, flags[0])) atomicAdd(&count[rows[e]], 1);
}

__global__ __launch_bounds__(256) void scan_blocks(const int* __restrict__ count,
                                                   int* __restrict__ rowptr,
                                                   int* __restrict__ partials) {
    __shared__ int s[256];
    int i = blockIdx.x * 256 + threadIdx.x;
    int v = (i < NNODE) ? count[i] : 0;
    s[threadIdx.x] = v;
    __syncthreads();
    for (int off = 1; off < 256; off <<= 1) {
        int t = (threadIdx.x >= off) ? s[threadIdx.x - off] : 0;
        __syncthreads();
        s[threadIdx.x] += t;
        __syncthreads();
    }
    if (i < NNODE) rowptr[i + 1] = s[threadIdx.x];
    if (threadIdx.x == 255) partials[blockIdx.x] = s[255];
}

__global__ __launch_bounds__(1024) void scan_partials(int* __restrict__ partials) {
    __shared__ int s[1024];
    int v = (threadIdx.x < SCAN_BLOCKS) ? partials[threadIdx.x] : 0;
    s[threadIdx.x] = v;
    __syncthreads();
    for (int off = 1; off < 1024; off <<= 1) {
        int t = (threadIdx.x >= off) ? s[threadIdx.x - off] : 0;
        __syncthreads();
        s[threadIdx.x] += t;
        __syncthreads();
    }
    if (threadIdx.x < SCAN_BLOCKS) partials[threadIdx.x] = s[threadIdx.x] - v;
}

// rowptr[i+1] finalized; cursor[i] = rowptr[i] (scatter start positions)
__global__ __launch_bounds__(256) void add_back(int* __restrict__ rowptr,
                                                int* __restrict__ cursor,
                                                const int* __restrict__ partials) {
    int i = blockIdx.x * 256 + threadIdx.x;
    if (i >= NNODE) return;
    int v = rowptr[i + 1] + partials[blockIdx.x];
    rowptr[i + 1] = v;
    cursor[i + 1] = v;
    if (i == 0) { rowptr[0] = 0; cursor[0] = 0; }
}

// one packed 8B store per kept edge: low32 = col, high32 = f32 bits of 2*val
__global__ __launch_bounds__(256) void scatter_csr(const void* __restrict__ mask,
                                                   const int* __restrict__ rows,
                                                   const int* __restrict__ cols,
                                                   const void* __restrict__ adjv,
                                                   const int* __restrict__ flags,
                                                   int* __restrict__ cursor,
                                                   u64* __restrict__ edges) {
    int e = blockIdx.x * 256 + threadIdx.x;
    if (e >= NNZ) return;
    if (!keepE(mask, e, flags[0])) return;
    int pos = atomicAdd(&cursor[rows[e]], 1);
    float v = 2.0f * loadF(adjv, e, flags[2]);   // 1/(1-0.5) rescale
    u64 packed = ((u64)__float_as_uint(v) << 32) | (unsigned)cols[e];
    edges[pos] = packed;
}

// A = f32(concat(user_emb, item_emb))
__global__ __launch_bounds__(256) void concat_cast(const void* __restrict__ ue,
                                                   const void* __restrict__ ie,
                                                   const int* __restrict__ flags,
                                                   float* __restrict__ A) {
    long q = (long)blockIdx.x * 256 + threadIdx.x;   // float4 index
    const long NU4 = (long)NUSER * DIM / 4;
    const long NT4 = (long)NNODE * DIM / 4;
    if (q >= NT4) return;
    if (!flags[2]) {
        const f4* s = (q < NU4) ? (const f4*)ue : (const f4*)ie;
        long qi = (q < NU4) ? q : q - NU4;
        ((f4*)A)[q] = s[qi];
    } else {
        long i = q * 4;
        const long NU = NU4 * 4;
        for (int k = 0; k < 4; ++k)
            A[i + k] = (i + k < NU) ? loadF(ue, i + k, 1) : loadF(ie, i + k - NU, 1);
    }
}

// dst[r,:] = sum_j val[j] * src[col[j],:]
// One 64-lane wave per row. lane = q*16 + t: quarter q handles edges
// j0+q, j0+q+4, ...; lane covers dims [4t, 4t+4) via one f4 gather.
// Unroll-2 => 8 independent 16B gathers in flight per wave.
__global__ __launch_bounds__(256) void spmm_csr(const float* __restrict__ src,
                                                const int* __restrict__ rowptr,
                                                const u64* __restrict__ edges,
                                                float* __restrict__ dst) {
    int r = blockIdx.x * 4 + (threadIdx.x >> 6);
    if (r >= NNODE) return;
    int lane = threadIdx.x & 63;
    int q = lane >> 4;
    int t = lane & 15;
    int j0 = rowptr[r], j1 = rowptr[r + 1];
    f4 acc = {0.0f, 0.0f, 0.0f, 0.0f};
    int j = j0 + q;
    for (; j + 4 < j1; j += 8) {
        u64 e0 = edges[j];
        u64 e1 = edges[j + 4];
        int c0 = (int)(unsigned)e0;
        int c1 = (int)(unsigned)e1;
        float v0 = __uint_as_float((unsigned)(e0 >> 32));
        float v1 = __uint_as_float((unsigned)(e1 >> 32));
        f4 s0 = ((const f4*)(src + (size_t)c0 * DIM))[t];
        f4 s1 = ((const f4*)(src + (size_t)c1 * DIM))[t];
        acc += v0 * s0;
        acc += v1 * s1;
    }
    if (j < j1) {
        u64 e0 = edges[j];
        int c0 = (int)(unsigned)e0;
        float v0 = __uint_as_float((unsigned)(e0 >> 32));
        acc += v0 * ((const f4*)(src + (size_t)c0 * DIM))[t];
    }
    // reduce across quarters (lanes t, t+16, t+32, t+48)
    acc.x += __shfl_xor(acc.x, 16); acc.y += __shfl_xor(acc.y, 16);
    acc.z += __shfl_xor(acc.z, 16); acc.w += __shfl_xor(acc.w, 16);
    acc.x += __shfl_xor(acc.x, 32); acc.y += __shfl_xor(acc.y, 32);
    acc.z += __shfl_xor(acc.z, 32); acc.w += __shfl_xor(acc.w, 32);
    if (q == 0)
        __builtin_nontemporal_store(acc, (f4*)(dst + (size_t)r * DIM) + t);
}

// acc[b,:] += table[node(b),:]
__global__ __launch_bounds__(256) void gather_add(const float* __restrict__ table,
                                                  const int* __restrict__ users,
                                                  const int* __restrict__ items,
                                                  const int* __restrict__ flags,
                                                  float* __restrict__ acc) {
    int t = blockIdx.x * 256 + threadIdx.x;          // float4 index
    if (t >= 2 * BATCH * DIM / 4) return;
    int b = t >> 4;
    int d4 = t & 15;
    int sh = flags[1];
    long node;
    if (b < BATCH) node = (long)users[(size_t)b << sh];
    else           node = (long)NUSER + (long)items[(size_t)(b - BATCH) << sh];
    f4 a = ((f4*)acc)[t];
    a += ((const f4*)(table + node * DIM))[d4];
    ((f4*)acc)[t] = a;
}

// out = 0.25 * (acc + table[node])   (fused last gather + scale)
__global__ __launch_bounds__(256) void gather_final(const float* __restrict__ table,
                                                    const int* __restrict__ users,
                                                    const int* __restrict__ items,
                                                    const int* __restrict__ flags,
                                                    const float* __restrict__ acc,
                                                    float* __restrict__ out) {
    int t = blockIdx.x * 256 + threadIdx.x;          // float4 index
    if (t >= 2 * BATCH * DIM / 4) return;
    int b = t >> 4;
    int d4 = t & 15;
    int sh = flags[1];
    long node;
    if (b < BATCH) node = (long)users[(size_t)b << sh];
    else           node = (long)NUSER + (long)items[(size_t)(b - BATCH) << sh];
    f4 a = ((const f4*)acc)[t];
    a += ((const f4*)(table + node * DIM))[d4];
    a *= 0.25f;
    __builtin_nontemporal_store(a, (f4*)out + t);
}

extern "C" void kernel_launch(void* const* d_in, const int* in_sizes, int n_in,
                              void* d_out, int out_size, void* d_ws, size_t ws_size,
                              hipStream_t stream) {
    const void* user_emb = d_in[0];
    const void* item_emb = d_in[1];
    const void* adj_val  = d_in[2];
    const int*  adj_row  = (const int*)d_in[3];
    const int*  adj_col  = (const int*)d_in[4];
    const void* drop_msk = d_in[5];
    const int*  users    = (const int*)d_in[6];
    const int*  items    = (const int*)d_in[7];
    float* out = (float*)d_out;

    char* ws = (char*)d_ws;
    size_t off = 0;
    int* flags = (int*)(ws + off);            off += 256;
    float* out_acc = (float*)(ws + off);      off += (size_t)2 * BATCH * DIM * 4;   // 8 MB
    float* A = (float*)(ws + off);            off += (size_t)NNODE * DIM * 4;       // 38.4 MB
    float* B = (float*)(ws + off);            off += (size_t)NNODE * DIM * 4;       // 38.4 MB
    int* rowptr = (int*)(ws + off);           off += 600064;
    int* count = (int*)(ws + off);            off += 600064;
    int* cursor = (int*)(ws + off);           off += 600064;
    int* partials = (int*)(ws + off);         off += 4096;
    u64* edges = (u64*)(ws + off);            off += (size_t)NNZ * 8;               // 32 MB

    const int OUTN4 = 2 * BATCH * DIM / 4;            // 524288
    const int GOUT = (OUTN4 + 255) / 256;             // 2048
    const int GEDGE = (NNZ + 255) / 256;

    (void)hipMemsetAsync(count, 0, (size_t)NNODE * 4, stream);
    (void)hipMemsetAsync(out_acc, 0, (size_t)2 * BATCH * DIM * 4, stream);

    detect_fmt<<<1, 256, 0, stream>>>((const unsigned int*)drop_msk,
                                      (const unsigned int*)users,
                                      (const unsigned int*)adj_val, flags);
    hist_kept<<<GEDGE, 256, 0, stream>>>(drop_msk, adj_row, flags, count);
    scan_blocks<<<SCAN_BLOCKS, 256, 0, stream>>>(count, rowptr, partials);
    scan_partials<<<1, 1024, 0, stream>>>(partials);
    add_back<<<SCAN_BLOCKS, 256, 0, stream>>>(rowptr, cursor, partials);
    scatter_csr<<<GEDGE, 256, 0, stream>>>(drop_msk, adj_row, adj_col, adj_val,
                                           flags, cursor, edges);
    concat_cast<<<((NNODE * DIM / 4) + 255) / 256, 256, 0, stream>>>(user_emb, item_emb,
                                                                     flags, A);

    gather_add<<<GOUT, 256, 0, stream>>>(A, users, items, flags, out_acc);
    float* src = A;
    float* dst = B;
    for (int l = 0; l < 3; ++l) {
        spmm_csr<<<(NNODE + 3) / 4, 256, 0, stream>>>(src, rowptr, edges, dst);
        if (l < 2) {
            gather_add<<<GOUT, 256, 0, stream>>>(dst, users, items, flags, out_acc);
        } else {
            gather_final<<<GOUT, 256, 0, stream>>>(dst, users, items, flags, out_acc, out);
        }
        float* t = src; src = dst; dst = t;
    }
}